// Round 14
// baseline (160.369 us; speedup 1.0000x reference)
//
#include <hip/hip_runtime.h>
#include <math.h>

#define HEADS 4
#define DK 64
#define HD 256

typedef __attribute__((ext_vector_type(8))) __bf16 bf16x8;
typedef __attribute__((ext_vector_type(4))) float floatx4;

__device__ __forceinline__ ushort f2bf(float f) {
  union { float f; unsigned u; } x; x.f = f;
  return (ushort)((x.u + 0x7FFF + ((x.u >> 16) & 1)) >> 16);  // RNE
}

#if __has_builtin(__builtin_amdgcn_exp2f)
#define EXP2(x) __builtin_amdgcn_exp2f(x)
#else
#define EXP2(x) exp2f(x)
#endif

// pack two floats to bf16 pair in ONE VALU op (T12)
__device__ __forceinline__ unsigned cvtpk_bf16(float lo, float hi) {
  unsigned r;
  asm("v_cvt_pk_bf16_f32 %0, %1, %2" : "=v"(r) : "v"(lo), "v"(hi));
  return r;
}

// async global->LDS: dest = wave-uniform base + lane*16
#define GLDS(g, l) __builtin_amdgcn_global_load_lds(                      \
    (const __attribute__((address_space(1))) unsigned*)(g),               \
    (__attribute__((address_space(3))) unsigned*)(l), 16, 0, 0)

// ---------------------------------------------------------------------------
// S0: fp32 -> bf16 granule-swizzled convert for go, node_h, and 4 weights.
// (R18-exact)
// ---------------------------------------------------------------------------
__global__ __launch_bounds__(256) void cvt_fused(
    const float* __restrict__ go, const float* __restrict__ nh,
    const float* __restrict__ w0, const float* __restrict__ w1,
    const float* __restrict__ w2, const float* __restrict__ w3,
    ushort* __restrict__ gobf, ushort* __restrict__ nodebf,
    ushort* __restrict__ wbf, int T, int N) {
  const int idx = blockIdx.x * 256 + threadIdx.x;
  const int row = idx >> 5, gr = idx & 31;
  if (row >= T + N + 4 * 256) return;
  const float* x; ushort* y; int r = row;
  if (row < T) { x = go; y = gobf; }
  else if (row < T + N) { x = nh; y = nodebf; r = row - T; }
  else {
    const int wr = row - T - N, wi = wr >> 8;
    r = wr & 255;
    x = (wi == 0) ? w0 : (wi == 1) ? w1 : (wi == 2) ? w2 : w3;
    y = wbf + (size_t)wi * HD * HD;
  }
  const int chunk = gr >> 3, g = gr & 7;
  const float* src = x + (size_t)r * 256 + gr * 8;
  float4 a = *(const float4*)src;
  float4 bq = *(const float4*)(src + 4);
  ushort* dst = y + (size_t)r * 256 + chunk * 64 + (g ^ (r & 7)) * 8;
  union { ushort4 h[2]; uint4 q; } pk;
  pk.h[0] = (ushort4){f2bf(a.x), f2bf(a.y), f2bf(a.z), f2bf(a.w)};
  pk.h[1] = (ushort4){f2bf(bq.x), f2bf(bq.y), f2bf(bq.z), f2bf(bq.w)};
  *(uint4*)dst = pk.q;
}

// ---------------------------------------------------------------------------
// GEMM tile device fn (R18-exact): C_tile[m0:+128, n0:+16*NW*2] = A @ W^T.
// mode 0: bf16 plain. 1: bf16 + granule swizzle. 2: bf16 V^T node-swizzled.
// ---------------------------------------------------------------------------
template <int NW>
__device__ __forceinline__ void gemm_tile(const ushort* __restrict__ A,
                                          const ushort* __restrict__ W,
                                          ushort* __restrict__ C, int m0,
                                          int n0, int mode, int ldc,
                                          ushort* As, ushort* Ws, int lane,
                                          int w, int quad, int l15) {
  const int wm = w & 1, wn = w >> 1;
  floatx4 acc[4][NW];
#pragma unroll
  for (int mt = 0; mt < 4; ++mt)
#pragma unroll
    for (int nt = 0; nt < NW; ++nt) acc[mt][nt] = (floatx4){0.f, 0.f, 0.f, 0.f};

  for (int k0 = 0; k0 < 256; k0 += 64) {
    __syncthreads();
#pragma unroll
    for (int t = 0; t < 4; ++t)
      GLDS(A + (size_t)(m0 + w * 32 + t * 8 + (lane >> 3)) * 256 + k0 + (lane & 7) * 8,
           &As[(w * 32 + t * 8) * 64]);
#pragma unroll
    for (int t = 0; t < NW; ++t)
      GLDS(W + (size_t)(n0 + w * (8 * NW) + t * 8 + (lane >> 3)) * 256 + k0 + (lane & 7) * 8,
           &Ws[(w * (8 * NW) + t * 8) * 64]);
    __syncthreads();

#pragma unroll
    for (int kk = 0; kk < 2; ++kk) {
      const int pg = ((kk * 4 + quad) ^ (l15 & 7)) * 8;
      bf16x8 af[4], bfr[NW];
#pragma unroll
      for (int mt = 0; mt < 4; ++mt)
        af[mt] = *(const bf16x8*)&As[(wm * 64 + mt * 16 + l15) * 64 + pg];
#pragma unroll
      for (int nt = 0; nt < NW; ++nt)
        bfr[nt] = *(const bf16x8*)&Ws[(wn * (16 * NW) + nt * 16 + l15) * 64 + pg];
#pragma unroll
      for (int mt = 0; mt < 4; ++mt)
#pragma unroll
        for (int nt = 0; nt < NW; ++nt)
          acc[mt][nt] = __builtin_amdgcn_mfma_f32_16x16x32_bf16(
              af[mt], bfr[nt], acc[mt][nt], 0, 0, 0);
    }
  }

#pragma unroll
  for (int mt = 0; mt < 4; ++mt)
#pragma unroll
    for (int nt = 0; nt < NW; ++nt) {
      const int col = n0 + wn * (16 * NW) + nt * 16 + l15;
      if (mode == 2) {
        const int d = col & 63;
        const int g = mt * 2 + (quad >> 1);
        const int node = m0 + wm * 64 + (g ^ (d & 7)) * 8 + (quad & 1) * 4;
        ushort4 o = {f2bf(acc[mt][nt][0]), f2bf(acc[mt][nt][1]),
                     f2bf(acc[mt][nt][2]), f2bf(acc[mt][nt][3])};
        *(ushort4*)&C[(size_t)col * ldc + node] = o;
      } else {
#pragma unroll
        for (int r = 0; r < 4; ++r) {
          const int row = m0 + wm * 64 + mt * 16 + quad * 4 + r;
          int cc = col;
          if (mode == 1)
            cc = (col & ~63) | (((((col >> 3) & 7) ^ (row & 7))) << 3) | (col & 7);
          C[(size_t)row * 256 + cc] = f2bf(acc[mt][nt][r]);
        }
      }
    }
}

// ---------------------------------------------------------------------------
// S1: fused Q/K/V projection GEMMs (R18-exact): NW=4, grid 784.
// XCD co-location: both n0-tiles of a panel congruent mod 8 (NT=392).
// ---------------------------------------------------------------------------
__global__ __launch_bounds__(256) void qkv_gemm(const ushort* __restrict__ gobf,
                                                const ushort* __restrict__ nodebf,
                                                const ushort* __restrict__ wbf,
                                                ushort* __restrict__ Qbf,
                                                ushort* __restrict__ Kgb,
                                                ushort* __restrict__ Vtb,
                                                int T, int N) {
  __shared__ __align__(16) ushort As[128 * 64];
  __shared__ __align__(16) ushort Ws[128 * 64];
  const int tid = threadIdx.x, lane = tid & 63, w = tid >> 6;
  const int quad = lane >> 4, l15 = lane & 15;
  const int QX = T >> 7, KB = N >> 7;
  const int NT = QX + 2 * KB;                  // 392 (== 0 mod 8)
  const int jx = blockIdx.x % NT;              // tile row (A-panel id)
  const int n0 = (blockIdx.x / NT) * 128;      // output column (0 or 128)
  if (jx < QX)
    gemm_tile<4>(gobf, wbf, Qbf, jx * 128, n0, 0, 0, As, Ws, lane, w, quad, l15);
  else if (jx < QX + KB)
    gemm_tile<4>(nodebf, wbf + (size_t)HD * HD, Kgb, (jx - QX) * 128, n0, 1, 0,
                 As, Ws, lane, w, quad, l15);
  else
    gemm_tile<4>(nodebf, wbf + (size_t)2 * HD * HD, Vtb, (jx - QX - KB) * 128,
                 n0, 2, N, As, Ws, lane, w, quad, l15);
}

// ---------------------------------------------------------------------------
// S2: split-K MFMA flash attention — R22: V DIRECT FROM L2 (Vs LDS deleted).
// R13's direct-fragment failure was K (needed immediately post-barrier,
// latency exposed). V is consumed only at PV — the LAST phase — so global
// ->reg V loads issued right after the barrier have the whole QK+softmax
// phase (~1000 cyc) to cover L2 latency (~200-300). The V^T layout gives
// each lane a contiguous aligned 16B fragment (same bytes Vs staging
// copied). Removes per chunk/block: 8 GLDS + 32 ds_read_b128 (~1/3 of the
// LDS pipe); LDS 32 -> 16 KB. V reads go 4x redundant across waves but
// are L2-resident (R11: FETCH ~15 MB — the invariant to check).
// K staging/barrier dbuf, in-register P transpose, cvt_pk, setprio,
// entry stagger all R18-exact.
// ---------------------------------------------------------------------------
__global__ __launch_bounds__(256, 3) void attn_split(
    const ushort* __restrict__ Qb, const ushort* __restrict__ Kg,
    const ushort* __restrict__ Vt, const int* __restrict__ lens,
    float* __restrict__ Opart, float* __restrict__ Lpart,
    int T, int N, int B) {
  __shared__ __align__(16) ushort Ks[2][64 * 64];   // [key][dk] phys granules

  const int tid = threadIdx.x, lane = tid & 63, wave = tid >> 6;
  const int quad = lane >> 4, l15 = lane & 15;
  const int QX = T >> 7;
  const int nspl = N >> 10;
  const int grpc = HEADS * nspl;       // 96 == 0 mod 8 -> qx copies co-located
  const int qx = blockIdx.x / grpc;
  const int rem = blockIdx.x - qx * grpc;
  const int h = rem / nspl;
  const int zid = rem - h * nspl;

  // map split id -> (segment b, key offset): 1024-key units
  int z = zid, b, start = 0, len = 0, off = -1;
  for (b = 0; b < B; ++b) {
    len = lens[b];
    const int s = (len + 1023) >> 10;
    if (z < s) { off = z << 10; break; }
    z -= s; start += len;
  }
  if (off < 0) return;
  const int kcnt = min(1024, len - off);
  const int kbeg = start + off;

  // phase stagger — co-residency rank = blockIdx.x >> 8 (0,1,2)
  for (int i = (int)(blockIdx.x >> 8); i > 0; --i)
    __builtin_amdgcn_s_sleep(35);

  const int q0 = qx * 128 + wave * 32;
  bf16x8 qb[2][2];
#pragma unroll
  for (int qt = 0; qt < 2; ++qt)
#pragma unroll
    for (int kk = 0; kk < 2; ++kk)
      qb[qt][kk] = *(const bf16x8*)(Qb + (size_t)(q0 + qt * 16 + l15) * 256 +
                                    h * 64 + kk * 32 + quad * 8);

  floatx4 o[2][4];
#pragma unroll
  for (int qt = 0; qt < 2; ++qt)
#pragma unroll
    for (int nt = 0; nt < 4; ++nt) o[qt][nt] = (floatx4){0.f, 0.f, 0.f, 0.f};
  float lsum[2] = {0.f, 0.f};

  const float sc = 0.18033688011112042f;  // log2(e) / (sqrt(64)*TEMP)
  const int srow = lane >> 3;
  const int scol = (lane & 7) * 8;

  // per-lane V fragment base pointers (contiguous 16B frags in V^T layout)
  const ushort* vfb[2][4];
#pragma unroll
  for (int ks = 0; ks < 2; ++ks)
#pragma unroll
    for (int nt = 0; nt < 4; ++nt)
      vfb[ks][nt] = Vt + (size_t)(h * 64 + nt * 16 + l15) * (size_t)N + kbeg +
                    ((ks * 4 + quad) ^ (l15 & 7)) * 8;

  // prefetch K chunk 0 into buffer 0
  GLDS(Kg + (size_t)(kbeg + wave * 8 + srow) * 256 + h * 64 + scol,
       &Ks[0][(wave * 8) * 64]);
  GLDS(Kg + (size_t)(kbeg + wave * 8 + 32 + srow) * 256 + h * 64 + scol,
       &Ks[0][(wave * 8 + 32) * 64]);

  int buf = 0;
  for (int j0 = 0; j0 < kcnt; j0 += 64, buf ^= 1) {
    __syncthreads();  // drains vmcnt -> K buffer `buf` ready
    const int jn = j0 + 64;
    if (jn < kcnt) {  // prefetch next K chunk into other buffer
      GLDS(Kg + (size_t)(kbeg + jn + wave * 8 + srow) * 256 + h * 64 + scol,
           &Ks[buf ^ 1][(wave * 8) * 64]);
      GLDS(Kg + (size_t)(kbeg + jn + wave * 8 + 32 + srow) * 256 + h * 64 + scol,
           &Ks[buf ^ 1][(wave * 8 + 32) * 64]);
    }

    // V fragments of THIS chunk: issue now, consumed at PV (latency hidden
    // under QK + softmax)
    bf16x8 vf[2][4];
#pragma unroll
    for (int ks = 0; ks < 2; ++ks)
#pragma unroll
      for (int nt = 0; nt < 4; ++nt)
        vf[ks][nt] = *(const bf16x8*)(vfb[ks][nt] + j0);

    // S^T[64 keys x 32 q]: A=K-frag (m=key), B=Q-frag (n=q)
    floatx4 st[4][2];
#pragma unroll
    for (int t = 0; t < 4; ++t)
#pragma unroll
      for (int qt = 0; qt < 2; ++qt) st[t][qt] = (floatx4){0.f, 0.f, 0.f, 0.f};
    __builtin_amdgcn_s_setprio(1);
#pragma unroll
    for (int kk = 0; kk < 2; ++kk) {
#pragma unroll
      for (int t = 0; t < 4; ++t) {
        bf16x8 kf = *(const bf16x8*)&Ks[buf][(t * 16 + l15) * 64 +
                                            ((kk * 4 + quad) ^ (l15 & 7)) * 8];
        st[t][0] = __builtin_amdgcn_mfma_f32_16x16x32_bf16(kf, qb[0][kk], st[t][0], 0, 0, 0);
        st[t][1] = __builtin_amdgcn_mfma_f32_16x16x32_bf16(kf, qb[1][kk], st[t][1], 0, 0, 0);
      }
    }
    __builtin_amdgcn_s_setprio(0);

    // fixed-shift softmax -> packed bf16 dwords kept in REGISTERS
    unsigned W[4][2][2];
    if (jn <= kcnt) {
#pragma unroll
      for (int t = 0; t < 4; ++t)
#pragma unroll
        for (int qt = 0; qt < 2; ++qt) {
          float p[4];
#pragma unroll
          for (int r = 0; r < 4; ++r) p[r] = EXP2(fmaf(st[t][qt][r], sc, -32.0f));
          lsum[qt] += (p[0] + p[1]) + (p[2] + p[3]);
          W[t][qt][0] = cvtpk_bf16(p[0], p[1]);
          W[t][qt][1] = cvtpk_bf16(p[2], p[3]);
        }
    } else {
#pragma unroll
      for (int t = 0; t < 4; ++t)
#pragma unroll
        for (int qt = 0; qt < 2; ++qt) {
          float p[4];
#pragma unroll
          for (int r = 0; r < 4; ++r) {
            const bool v = (j0 + t * 16 + quad * 4 + r) < kcnt;
            p[r] = v ? EXP2(fmaf(st[t][qt][r], sc, -32.0f)) : 0.0f;
          }
          lsum[qt] += (p[0] + p[1]) + (p[2] + p[3]);
          W[t][qt][0] = cvtpk_bf16(p[0], p[1]);
          W[t][qt][1] = cvtpk_bf16(p[2], p[3]);
        }
    }

    // O[32q x 64d] += P * V. A-frag built in-register via permlane swaps.
#pragma unroll
    for (int ks = 0; ks < 2; ++ks) {
      bf16x8 pa[2];
#pragma unroll
      for (int qt = 0; qt < 2; ++qt) {
        unsigned a0 = W[2 * ks][qt][0], a1 = W[2 * ks][qt][1];
        unsigned b0 = W[2 * ks + 1][qt][0], b1 = W[2 * ks + 1][qt][1];
        asm("v_permlane32_swap_b32 %0, %1" : "+v"(a0), "+v"(b0));
        asm("v_permlane32_swap_b32 %0, %1" : "+v"(a1), "+v"(b1));
        asm("v_permlane16_swap_b32 %0, %1" : "+v"(a0), "+v"(b0));
        asm("v_permlane16_swap_b32 %0, %1" : "+v"(a1), "+v"(b1));
        union { uint4 u; bf16x8 v; } c;
        c.u = make_uint4(a0, a1, b0, b1);
        pa[qt] = c.v;
      }
      __builtin_amdgcn_s_setprio(1);
#pragma unroll
      for (int nt = 0; nt < 4; ++nt) {
        o[0][nt] = __builtin_amdgcn_mfma_f32_16x16x32_bf16(pa[0], vf[ks][nt], o[0][nt], 0, 0, 0);
        o[1][nt] = __builtin_amdgcn_mfma_f32_16x16x32_bf16(pa[1], vf[ks][nt], o[1][nt], 0, 0, 0);
      }
      __builtin_amdgcn_s_setprio(0);
    }
  }

  // epilogue: UNNORMALIZED fp32 partials (full-line stores)
  const int part = (zid * HEADS + h) * QX + qx;
  float* op = Opart + (size_t)part * 8192;
#pragma unroll
  for (int qt = 0; qt < 2; ++qt) {
#pragma unroll
    for (int nt = 0; nt < 4; ++nt)
#pragma unroll
      for (int r = 0; r < 4; ++r)
        op[(wave * 32 + qt * 16 + quad * 4 + r) * 64 + nt * 16 + l15] = o[qt][nt][r];
    float lt = lsum[qt];
    lt += __shfl_xor(lt, 16);
    lt += __shfl_xor(lt, 32);
    if (lane < 16)
      Lpart[(size_t)part * 128 + wave * 32 + qt * 16 + lane] = lt;
  }
}

// ---------------------------------------------------------------------------
// S3+S4 fused (R18-exact): combine -> ctx tile in LDS, then proj GEMM.
// ---------------------------------------------------------------------------
__global__ __launch_bounds__(256) void combine_proj(
    const float* __restrict__ Opart, const float* __restrict__ Lpart,
    const int* __restrict__ lens, const ushort* __restrict__ wproj,
    float* __restrict__ outp, int T) {
  __shared__ __align__(16) ushort Cs[64 * 256];  // ctx tile [row][k phys]
  __shared__ __align__(16) ushort Ws[64 * 256];  // W panel  [col][k phys]

  const int t = threadIdx.x;
  // ---- phase 1: combine -> Cs ----
  {
    const int lrow = t >> 2;
    const int h = t & 3;
    const int row = blockIdx.x * 64 + lrow;
    const int b = row / T;
    const int tq = row - b * T;
    const int qx = tq >> 7, qr = tq & 127;
    const int QX = T >> 7;
    int z0 = 0;
    for (int i = 0; i < b; ++i) z0 += (lens[i] + 1023) >> 10;
    const int ns = (lens[b] + 1023) >> 10;

    float l = 0.f;
    float4 acc[16];
#pragma unroll
    for (int g = 0; g < 16; ++g) acc[g] = make_float4(0.f, 0.f, 0.f, 0.f);
    for (int s = 0; s < ns; ++s) {
      const size_t part = (size_t)((z0 + s) * HEADS + h) * QX + qx;
      l += Lpart[part * 128 + qr];
      const float4* src = (const float4*)(Opart + part * 8192 + (size_t)qr * 64);
#pragma unroll
      for (int g = 0; g < 16; ++g) {
        float4 v = src[g];
        acc[g].x += v.x; acc[g].y += v.y; acc[g].z += v.z; acc[g].w += v.w;
      }
    }
    const float inv = 1.0f / l;
    ushort* dst = &Cs[lrow * 256 + h * 64];
#pragma unroll
    for (int gg = 0; gg < 8; ++gg) {
      const float4 a = acc[gg * 2], c = acc[gg * 2 + 1];
      const int phys = gg ^ (lrow & 7);
      ushort4 o0 = {f2bf(a.x * inv), f2bf(a.y * inv), f2bf(a.z * inv), f2bf(a.w * inv)};
      ushort4 o1 = {f2bf(c.x * inv), f2bf(c.y * inv), f2bf(c.z * inv), f2bf(c.w * inv)};
      *(ushort4*)&dst[phys * 8] = o0;
      *(ushort4*)&dst[phys * 8 + 4] = o1;
    }
  }

  // ---- phase 2: out[64 rows][256] = Cs @ Wproj^T ----
  const int lane = t & 63, w = t >> 6;
  const int quad = lane >> 4, l15 = lane & 15;
  const size_t row0 = (size_t)blockIdx.x * 64;

  for (int n0c = 0; n0c < 256; n0c += 64) {
    __syncthreads();  // phase-1 done / previous panel's compute done
#pragma unroll
    for (int tt = 0; tt < 8; ++tt)
      GLDS(wproj + (size_t)(n0c + w * 16 + tt * 2 + (lane >> 5)) * 256 + (lane & 31) * 8,
           &Ws[(w * 16 + tt * 2) * 256]);
    __syncthreads();  // drain

    floatx4 oacc[4];
#pragma unroll
    for (int nt = 0; nt < 4; ++nt) oacc[nt] = (floatx4){0.f, 0.f, 0.f, 0.f};
#pragma unroll
    for (int c = 0; c < 4; ++c)
#pragma unroll
      for (int kk = 0; kk < 2; ++kk) {
        const int pg = ((kk * 4 + quad) ^ (l15 & 7)) * 8;
        bf16x8 af = *(const bf16x8*)&Cs[(w * 16 + l15) * 256 + c * 64 + pg];
#pragma unroll
        for (int nt = 0; nt < 4; ++nt) {
          bf16x8 bfr = *(const bf16x8*)&Ws[(nt * 16 + l15) * 256 + c * 64 + pg];
          oacc[nt] = __builtin_amdgcn_mfma_f32_16x16x32_bf16(af, bfr, oacc[nt], 0, 0, 0);
        }
      }
#pragma unroll
    for (int nt = 0; nt < 4; ++nt)
#pragma unroll
      for (int r = 0; r < 4; ++r)
        outp[(row0 + w * 16 + quad * 4 + r) * 256 + n0c + nt * 16 + l15] = oacc[nt][r];
  }
}

// ---------------------------------------------------------------------------
extern "C" void kernel_launch(void* const* d_in, const int* in_sizes, int n_in,
                              void* d_out, int out_size, void* d_ws, size_t ws_size,
                              hipStream_t stream) {
  const float* go     = (const float*)d_in[0];
  const float* node_h = (const float*)d_in[1];
  const float* Wq     = (const float*)d_in[2];
  const float* Wk     = (const float*)d_in[3];
  const float* Wv     = (const float*)d_in[4];
  const float* Wproj  = (const float*)d_in[5];
  const int*   lens   = (const int*)d_in[6];

  const int T = in_sizes[0] / HD;   // 1024
  const int N = in_sizes[1] / HD;   // 24576
  const int B = in_sizes[6];        // 16
  const int NSPL = N >> 10;         // 24 (lens are multiples of 1024)
  const int QX = T >> 7;            // 8
  const int KB = N >> 7;            // 192

  // workspace carve; Opart/Lpart overlay nodebf (dead after QKV GEMMs)
  char* p = (char*)d_ws;
  ushort* Kgb  = (ushort*)p;  p += (size_t)N * HD * 2;       // 12.6 MB
  ushort* Vtb  = (ushort*)p;  p += (size_t)N * HD * 2;       // 12.6 MB
  ushort* Qbf  = (ushort*)p;  p += (size_t)T * HD * 2;
  ushort* gobf = (ushort*)p;  p += (size_t)T * HD * 2;
  ushort* ctxb = (ushort*)p;  p += (size_t)B * T * HD * 2;   // 8.4 MB (unused)
  ushort* wbf  = (ushort*)p;  p += (size_t)4 * HD * HD * 2;
  ushort* nodebf = (ushort*)p;                               // 12.6 MB ...
  float* Opart = (float*)p;   p += (size_t)NSPL * HEADS * QX * 8192 * 4;  // 25.2 MB
  float* Lpart = (float*)p;   p += (size_t)NSPL * HEADS * QX * 128 * 4;   // 0.4 MB
  (void)ctxb;

  cvt_fused<<<((T + N + 1024) * 32 + 255) / 256, 256, 0, stream>>>(
      go, node_h, Wq, Wk, Wv, Wproj, gobf, nodebf, wbf, T, N);

  qkv_gemm<<<(QX + 2 * KB) * 2, 256, 0, stream>>>(gobf, nodebf, wbf, Qbf, Kgb,
                                                  Vtb, T, N);

  attn_split<<<QX * HEADS * NSPL, 256, 0, stream>>>(Qbf, Kgb, Vtb, lens,
                                                    Opart, Lpart, T, N, B);

  combine_proj<<<(B * T) / 64, 256, 0, stream>>>(Opart, Lpart, lens,
                                                 wbf + (size_t)3 * HD * HD,
                                                 (float*)d_out, T);
}

// Round 15
// 151.755 us; speedup vs baseline: 1.0568x; 1.0568x over previous
//
#include <hip/hip_runtime.h>
#include <math.h>

#define HEADS 4
#define DK 64
#define HD 256

typedef __attribute__((ext_vector_type(8))) __bf16 bf16x8;
typedef __attribute__((ext_vector_type(4))) float floatx4;

__device__ __forceinline__ ushort f2bf(float f) {
  union { float f; unsigned u; } x; x.f = f;
  return (ushort)((x.u + 0x7FFF + ((x.u >> 16) & 1)) >> 16);  // RNE
}

#if __has_builtin(__builtin_amdgcn_exp2f)
#define EXP2(x) __builtin_amdgcn_exp2f(x)
#else
#define EXP2(x) exp2f(x)
#endif

// pack two floats to bf16 pair in ONE VALU op (T12)
__device__ __forceinline__ unsigned cvtpk_bf16(float lo, float hi) {
  unsigned r;
  asm("v_cvt_pk_bf16_f32 %0, %1, %2" : "=v"(r) : "v"(lo), "v"(hi));
  return r;
}

// async global->LDS: dest = wave-uniform base + lane*16
#define GLDS(g, l) __builtin_amdgcn_global_load_lds(                      \
    (const __attribute__((address_space(1))) unsigned*)(g),               \
    (__attribute__((address_space(3))) unsigned*)(l), 16, 0, 0)

// ---------------------------------------------------------------------------
// S0: fp32 -> bf16 granule-swizzled convert for go, node_h, and 4 weights.
// (R18-exact)
// ---------------------------------------------------------------------------
__global__ __launch_bounds__(256) void cvt_fused(
    const float* __restrict__ go, const float* __restrict__ nh,
    const float* __restrict__ w0, const float* __restrict__ w1,
    const float* __restrict__ w2, const float* __restrict__ w3,
    ushort* __restrict__ gobf, ushort* __restrict__ nodebf,
    ushort* __restrict__ wbf, int T, int N) {
  const int idx = blockIdx.x * 256 + threadIdx.x;
  const int row = idx >> 5, gr = idx & 31;
  if (row >= T + N + 4 * 256) return;
  const float* x; ushort* y; int r = row;
  if (row < T) { x = go; y = gobf; }
  else if (row < T + N) { x = nh; y = nodebf; r = row - T; }
  else {
    const int wr = row - T - N, wi = wr >> 8;
    r = wr & 255;
    x = (wi == 0) ? w0 : (wi == 1) ? w1 : (wi == 2) ? w2 : w3;
    y = wbf + (size_t)wi * HD * HD;
  }
  const int chunk = gr >> 3, g = gr & 7;
  const float* src = x + (size_t)r * 256 + gr * 8;
  float4 a = *(const float4*)src;
  float4 bq = *(const float4*)(src + 4);
  ushort* dst = y + (size_t)r * 256 + chunk * 64 + (g ^ (r & 7)) * 8;
  union { ushort4 h[2]; uint4 q; } pk;
  pk.h[0] = (ushort4){f2bf(a.x), f2bf(a.y), f2bf(a.z), f2bf(a.w)};
  pk.h[1] = (ushort4){f2bf(bq.x), f2bf(bq.y), f2bf(bq.z), f2bf(bq.w)};
  *(uint4*)dst = pk.q;
}

// ---------------------------------------------------------------------------
// GEMM tile device fn (R18-exact): C_tile[m0:+128, n0:+16*NW*2] = A @ W^T.
// mode 0: bf16 plain. 1: bf16 + granule swizzle. 2: bf16 V^T node-swizzled.
// ---------------------------------------------------------------------------
template <int NW>
__device__ __forceinline__ void gemm_tile(const ushort* __restrict__ A,
                                          const ushort* __restrict__ W,
                                          ushort* __restrict__ C, int m0,
                                          int n0, int mode, int ldc,
                                          ushort* As, ushort* Ws, int lane,
                                          int w, int quad, int l15) {
  const int wm = w & 1, wn = w >> 1;
  floatx4 acc[4][NW];
#pragma unroll
  for (int mt = 0; mt < 4; ++mt)
#pragma unroll
    for (int nt = 0; nt < NW; ++nt) acc[mt][nt] = (floatx4){0.f, 0.f, 0.f, 0.f};

  for (int k0 = 0; k0 < 256; k0 += 64) {
    __syncthreads();
#pragma unroll
    for (int t = 0; t < 4; ++t)
      GLDS(A + (size_t)(m0 + w * 32 + t * 8 + (lane >> 3)) * 256 + k0 + (lane & 7) * 8,
           &As[(w * 32 + t * 8) * 64]);
#pragma unroll
    for (int t = 0; t < NW; ++t)
      GLDS(W + (size_t)(n0 + w * (8 * NW) + t * 8 + (lane >> 3)) * 256 + k0 + (lane & 7) * 8,
           &Ws[(w * (8 * NW) + t * 8) * 64]);
    __syncthreads();

#pragma unroll
    for (int kk = 0; kk < 2; ++kk) {
      const int pg = ((kk * 4 + quad) ^ (l15 & 7)) * 8;
      bf16x8 af[4], bfr[NW];
#pragma unroll
      for (int mt = 0; mt < 4; ++mt)
        af[mt] = *(const bf16x8*)&As[(wm * 64 + mt * 16 + l15) * 64 + pg];
#pragma unroll
      for (int nt = 0; nt < NW; ++nt)
        bfr[nt] = *(const bf16x8*)&Ws[(wn * (16 * NW) + nt * 16 + l15) * 64 + pg];
#pragma unroll
      for (int mt = 0; mt < 4; ++mt)
#pragma unroll
        for (int nt = 0; nt < NW; ++nt)
          acc[mt][nt] = __builtin_amdgcn_mfma_f32_16x16x32_bf16(
              af[mt], bfr[nt], acc[mt][nt], 0, 0, 0);
    }
  }

#pragma unroll
  for (int mt = 0; mt < 4; ++mt)
#pragma unroll
    for (int nt = 0; nt < NW; ++nt) {
      const int col = n0 + wn * (16 * NW) + nt * 16 + l15;
      if (mode == 2) {
        const int d = col & 63;
        const int g = mt * 2 + (quad >> 1);
        const int node = m0 + wm * 64 + (g ^ (d & 7)) * 8 + (quad & 1) * 4;
        ushort4 o = {f2bf(acc[mt][nt][0]), f2bf(acc[mt][nt][1]),
                     f2bf(acc[mt][nt][2]), f2bf(acc[mt][nt][3])};
        *(ushort4*)&C[(size_t)col * ldc + node] = o;
      } else {
#pragma unroll
        for (int r = 0; r < 4; ++r) {
          const int row = m0 + wm * 64 + mt * 16 + quad * 4 + r;
          int cc = col;
          if (mode == 1)
            cc = (col & ~63) | (((((col >> 3) & 7) ^ (row & 7))) << 3) | (col & 7);
          C[(size_t)row * 256 + cc] = f2bf(acc[mt][nt][r]);
        }
      }
    }
}

// ---------------------------------------------------------------------------
// S1: fused Q/K/V projection GEMMs (R18-exact): NW=4, grid 784.
// XCD co-location: both n0-tiles of a panel congruent mod 8 (NT=392).
// ---------------------------------------------------------------------------
__global__ __launch_bounds__(256) void qkv_gemm(const ushort* __restrict__ gobf,
                                                const ushort* __restrict__ nodebf,
                                                const ushort* __restrict__ wbf,
                                                ushort* __restrict__ Qbf,
                                                ushort* __restrict__ Kgb,
                                                ushort* __restrict__ Vtb,
                                                int T, int N) {
  __shared__ __align__(16) ushort As[128 * 64];
  __shared__ __align__(16) ushort Ws[128 * 64];
  const int tid = threadIdx.x, lane = tid & 63, w = tid >> 6;
  const int quad = lane >> 4, l15 = lane & 15;
  const int QX = T >> 7, KB = N >> 7;
  const int NT = QX + 2 * KB;                  // 392 (== 0 mod 8)
  const int jx = blockIdx.x % NT;              // tile row (A-panel id)
  const int n0 = (blockIdx.x / NT) * 128;      // output column (0 or 128)
  if (jx < QX)
    gemm_tile<4>(gobf, wbf, Qbf, jx * 128, n0, 0, 0, As, Ws, lane, w, quad, l15);
  else if (jx < QX + KB)
    gemm_tile<4>(nodebf, wbf + (size_t)HD * HD, Kgb, (jx - QX) * 128, n0, 1, 0,
                 As, Ws, lane, w, quad, l15);
  else
    gemm_tile<4>(nodebf, wbf + (size_t)2 * HD * HD, Vtb, (jx - QX - KB) * 128,
                 n0, 2, N, As, Ws, lane, w, quad, l15);
}

// ---------------------------------------------------------------------------
// S2: split-K MFMA flash attention — R18-exact (session best): in-register
// P transpose via permlane swaps, cvt_pk, setprio, entry stagger, shared
// K/V GLDS dbuf, zero bank conflicts.
// ---------------------------------------------------------------------------
__global__ __launch_bounds__(256, 3) void attn_split(
    const ushort* __restrict__ Qb, const ushort* __restrict__ Kg,
    const ushort* __restrict__ Vt, const int* __restrict__ lens,
    float* __restrict__ Opart, float* __restrict__ Lpart,
    int T, int N, int B) {
  __shared__ __align__(16) ushort Ks[2][64 * 64];   // [key][dk] phys granules
  __shared__ __align__(16) ushort Vs[2][64 * 64];   // [dk][key] phys granules

  const int tid = threadIdx.x, lane = tid & 63, wave = tid >> 6;
  const int quad = lane >> 4, l15 = lane & 15;
  const int QX = T >> 7;
  const int nspl = N >> 10;
  const int grpc = HEADS * nspl;       // 96 == 0 mod 8 -> qx copies co-located
  const int qx = blockIdx.x / grpc;
  const int rem = blockIdx.x - qx * grpc;
  const int h = rem / nspl;
  const int zid = rem - h * nspl;

  // map split id -> (segment b, key offset): 1024-key units
  int z = zid, b, start = 0, len = 0, off = -1;
  for (b = 0; b < B; ++b) {
    len = lens[b];
    const int s = (len + 1023) >> 10;
    if (z < s) { off = z << 10; break; }
    z -= s; start += len;
  }
  if (off < 0) return;
  const int kcnt = min(1024, len - off);
  const int kbeg = start + off;

  // phase stagger — co-residency rank = blockIdx.x >> 8 (0,1,2)
  for (int i = (int)(blockIdx.x >> 8); i > 0; --i)
    __builtin_amdgcn_s_sleep(35);

  const int q0 = qx * 128 + wave * 32;
  bf16x8 qb[2][2];
#pragma unroll
  for (int qt = 0; qt < 2; ++qt)
#pragma unroll
    for (int kk = 0; kk < 2; ++kk)
      qb[qt][kk] = *(const bf16x8*)(Qb + (size_t)(q0 + qt * 16 + l15) * 256 +
                                    h * 64 + kk * 32 + quad * 8);

  floatx4 o[2][4];
#pragma unroll
  for (int qt = 0; qt < 2; ++qt)
#pragma unroll
    for (int nt = 0; nt < 4; ++nt) o[qt][nt] = (floatx4){0.f, 0.f, 0.f, 0.f};
  float lsum[2] = {0.f, 0.f};

  const float sc = 0.18033688011112042f;  // log2(e) / (sqrt(64)*TEMP)
  const int srow = lane >> 3;
  const int scol = (lane & 7) * 8;

  // prefetch chunk 0 into buffer 0
  GLDS(Kg + (size_t)(kbeg + wave * 8 + srow) * 256 + h * 64 + scol,
       &Ks[0][(wave * 8) * 64]);
  GLDS(Kg + (size_t)(kbeg + wave * 8 + 32 + srow) * 256 + h * 64 + scol,
       &Ks[0][(wave * 8 + 32) * 64]);
  GLDS(Vt + (size_t)(h * 64 + wave * 8 + srow) * (size_t)N + kbeg + scol,
       &Vs[0][(wave * 8) * 64]);
  GLDS(Vt + (size_t)(h * 64 + wave * 8 + 32 + srow) * (size_t)N + kbeg + scol,
       &Vs[0][(wave * 8 + 32) * 64]);

  int buf = 0;
  for (int j0 = 0; j0 < kcnt; j0 += 64, buf ^= 1) {
    __syncthreads();  // drains vmcnt -> buffer `buf` ready
    const int jn = j0 + 64;
    if (jn < kcnt) {  // prefetch next chunk into other buffer during compute
      GLDS(Kg + (size_t)(kbeg + jn + wave * 8 + srow) * 256 + h * 64 + scol,
           &Ks[buf ^ 1][(wave * 8) * 64]);
      GLDS(Kg + (size_t)(kbeg + jn + wave * 8 + 32 + srow) * 256 + h * 64 + scol,
           &Ks[buf ^ 1][(wave * 8 + 32) * 64]);
      GLDS(Vt + (size_t)(h * 64 + wave * 8 + srow) * (size_t)N + kbeg + jn + scol,
           &Vs[buf ^ 1][(wave * 8) * 64]);
      GLDS(Vt + (size_t)(h * 64 + wave * 8 + 32 + srow) * (size_t)N + kbeg + jn + scol,
           &Vs[buf ^ 1][(wave * 8 + 32) * 64]);
    }

    // S^T[64 keys x 32 q]: A=K-frag (m=key), B=Q-frag (n=q)
    floatx4 st[4][2];
#pragma unroll
    for (int t = 0; t < 4; ++t)
#pragma unroll
      for (int qt = 0; qt < 2; ++qt) st[t][qt] = (floatx4){0.f, 0.f, 0.f, 0.f};
    __builtin_amdgcn_s_setprio(1);
#pragma unroll
    for (int kk = 0; kk < 2; ++kk) {
#pragma unroll
      for (int t = 0; t < 4; ++t) {
        bf16x8 kf = *(const bf16x8*)&Ks[buf][(t * 16 + l15) * 64 +
                                            ((kk * 4 + quad) ^ (l15 & 7)) * 8];
        st[t][0] = __builtin_amdgcn_mfma_f32_16x16x32_bf16(kf, qb[0][kk], st[t][0], 0, 0, 0);
        st[t][1] = __builtin_amdgcn_mfma_f32_16x16x32_bf16(kf, qb[1][kk], st[t][1], 0, 0, 0);
      }
    }
    __builtin_amdgcn_s_setprio(0);

    // fixed-shift softmax -> packed bf16 dwords kept in REGISTERS
    unsigned W[4][2][2];
    if (jn <= kcnt) {
#pragma unroll
      for (int t = 0; t < 4; ++t)
#pragma unroll
        for (int qt = 0; qt < 2; ++qt) {
          float p[4];
#pragma unroll
          for (int r = 0; r < 4; ++r) p[r] = EXP2(fmaf(st[t][qt][r], sc, -32.0f));
          lsum[qt] += (p[0] + p[1]) + (p[2] + p[3]);
          W[t][qt][0] = cvtpk_bf16(p[0], p[1]);
          W[t][qt][1] = cvtpk_bf16(p[2], p[3]);
        }
    } else {
#pragma unroll
      for (int t = 0; t < 4; ++t)
#pragma unroll
        for (int qt = 0; qt < 2; ++qt) {
          float p[4];
#pragma unroll
          for (int r = 0; r < 4; ++r) {
            const bool v = (j0 + t * 16 + quad * 4 + r) < kcnt;
            p[r] = v ? EXP2(fmaf(st[t][qt][r], sc, -32.0f)) : 0.0f;
          }
          lsum[qt] += (p[0] + p[1]) + (p[2] + p[3]);
          W[t][qt][0] = cvtpk_bf16(p[0], p[1]);
          W[t][qt][1] = cvtpk_bf16(p[2], p[3]);
        }
    }

    // O[32q x 64d] += P * V. A-frag built in-register via permlane swaps.
#pragma unroll
    for (int ks = 0; ks < 2; ++ks) {
      bf16x8 pa[2];
#pragma unroll
      for (int qt = 0; qt < 2; ++qt) {
        unsigned a0 = W[2 * ks][qt][0], a1 = W[2 * ks][qt][1];
        unsigned b0 = W[2 * ks + 1][qt][0], b1 = W[2 * ks + 1][qt][1];
        asm("v_permlane32_swap_b32 %0, %1" : "+v"(a0), "+v"(b0));
        asm("v_permlane32_swap_b32 %0, %1" : "+v"(a1), "+v"(b1));
        asm("v_permlane16_swap_b32 %0, %1" : "+v"(a0), "+v"(b0));
        asm("v_permlane16_swap_b32 %0, %1" : "+v"(a1), "+v"(b1));
        union { uint4 u; bf16x8 v; } c;
        c.u = make_uint4(a0, a1, b0, b1);
        pa[qt] = c.v;
      }
      __builtin_amdgcn_s_setprio(1);
#pragma unroll
      for (int nt = 0; nt < 4; ++nt) {
        bf16x8 vf = *(const bf16x8*)&Vs[buf][(nt * 16 + l15) * 64 +
                                            ((ks * 4 + quad) ^ (l15 & 7)) * 8];
        o[0][nt] = __builtin_amdgcn_mfma_f32_16x16x32_bf16(pa[0], vf, o[0][nt], 0, 0, 0);
        o[1][nt] = __builtin_amdgcn_mfma_f32_16x16x32_bf16(pa[1], vf, o[1][nt], 0, 0, 0);
      }
      __builtin_amdgcn_s_setprio(0);
    }
  }

  // epilogue: UNNORMALIZED fp32 partials (full-line stores)
  const int part = (zid * HEADS + h) * QX + qx;
  float* op = Opart + (size_t)part * 8192;
#pragma unroll
  for (int qt = 0; qt < 2; ++qt) {
#pragma unroll
    for (int nt = 0; nt < 4; ++nt)
#pragma unroll
      for (int r = 0; r < 4; ++r)
        op[(wave * 32 + qt * 16 + quad * 4 + r) * 64 + nt * 16 + l15] = o[qt][nt][r];
    float lt = lsum[qt];
    lt += __shfl_xor(lt, 16);
    lt += __shfl_xor(lt, 32);
    if (lane < 16)
      Lpart[(size_t)part * 128 + wave * 32 + qt * 16 + lane] = lt;
  }
}

// ---------------------------------------------------------------------------
// S3+S4 fused — R23: 32-ROW TILES, grid (B*T)/32 = 512 -> 2 blocks/CU
// (was 256 = 1/CU, 1 wave/SIMD — minimal latency hiding for a kernel
// streaming 42 MB + 4 serial staging panels). Phase 1: 2 threads per
// (row,head), 8 float4 halves each. LDS: Cs 16 KB + Ws 32 KB = 48 KB.
// Phase 2: per panel, wave w does row-tile (w&1), col pair (w>>1).
// Swizzle invariants hold (row/col tile offsets == 0 mod 8).
// ---------------------------------------------------------------------------
__global__ __launch_bounds__(256) void combine_proj(
    const float* __restrict__ Opart, const float* __restrict__ Lpart,
    const int* __restrict__ lens, const ushort* __restrict__ wproj,
    float* __restrict__ outp, int T) {
  __shared__ __align__(16) ushort Cs[32 * 256];  // ctx tile [row][k phys]
  __shared__ __align__(16) ushort Ws[64 * 256];  // W panel  [col][k phys]

  const int t = threadIdx.x;
  // ---- phase 1: combine -> Cs (thread = (row, head, half)) ----
  {
    const int lrow = t >> 3;
    const int h = (t >> 1) & 3;
    const int half = t & 1;
    const int row = blockIdx.x * 32 + lrow;
    const int b = row / T;
    const int tq = row - b * T;
    const int qx = tq >> 7, qr = tq & 127;
    const int QX = T >> 7;
    int z0 = 0;
    for (int i = 0; i < b; ++i) z0 += (lens[i] + 1023) >> 10;
    const int ns = (lens[b] + 1023) >> 10;

    float l = 0.f;
    float4 acc[8];
#pragma unroll
    for (int g = 0; g < 8; ++g) acc[g] = make_float4(0.f, 0.f, 0.f, 0.f);
    for (int s = 0; s < ns; ++s) {
      const size_t part = (size_t)((z0 + s) * HEADS + h) * QX + qx;
      l += Lpart[part * 128 + qr];
      const float4* src = (const float4*)(Opart + part * 8192 + (size_t)qr * 64) +
                          half * 8;
#pragma unroll
      for (int g = 0; g < 8; ++g) {
        float4 v = src[g];
        acc[g].x += v.x; acc[g].y += v.y; acc[g].z += v.z; acc[g].w += v.w;
      }
    }
    const float inv = 1.0f / l;
    ushort* dst = &Cs[lrow * 256 + h * 64];
#pragma unroll
    for (int g2 = 0; g2 < 4; ++g2) {
      const int gg = half * 4 + g2;
      const float4 a = acc[g2 * 2], c = acc[g2 * 2 + 1];
      const int phys = gg ^ (lrow & 7);
      ushort4 o0 = {f2bf(a.x * inv), f2bf(a.y * inv), f2bf(a.z * inv), f2bf(a.w * inv)};
      ushort4 o1 = {f2bf(c.x * inv), f2bf(c.y * inv), f2bf(c.z * inv), f2bf(c.w * inv)};
      *(ushort4*)&dst[phys * 8] = o0;
      *(ushort4*)&dst[phys * 8 + 4] = o1;
    }
  }

  // ---- phase 2: out[32 rows][256] = Cs @ Wproj^T ----
  const int lane = t & 63, w = t >> 6;
  const int quad = lane >> 4, l15 = lane & 15;
  const int rt = (w & 1) * 16;         // row-tile base within Cs
  const int ct = (w >> 1) * 32;        // col offset within panel
  const size_t row0 = (size_t)blockIdx.x * 32;

  for (int n0c = 0; n0c < 256; n0c += 64) {
    __syncthreads();  // phase-1 done / previous panel's compute done
#pragma unroll
    for (int tt = 0; tt < 8; ++tt)
      GLDS(wproj + (size_t)(n0c + w * 16 + tt * 2 + (lane >> 5)) * 256 + (lane & 31) * 8,
           &Ws[(w * 16 + tt * 2) * 256]);
    __syncthreads();  // drain

    floatx4 oacc[2];
#pragma unroll
    for (int nt = 0; nt < 2; ++nt) oacc[nt] = (floatx4){0.f, 0.f, 0.f, 0.f};
#pragma unroll
    for (int c = 0; c < 4; ++c)
#pragma unroll
      for (int kk = 0; kk < 2; ++kk) {
        const int pg = ((kk * 4 + quad) ^ (l15 & 7)) * 8;
        bf16x8 af = *(const bf16x8*)&Cs[(rt + l15) * 256 + c * 64 + pg];
#pragma unroll
        for (int nt = 0; nt < 2; ++nt) {
          bf16x8 bfr = *(const bf16x8*)&Ws[(ct + nt * 16 + l15) * 256 + c * 64 + pg];
          oacc[nt] = __builtin_amdgcn_mfma_f32_16x16x32_bf16(af, bfr, oacc[nt], 0, 0, 0);
        }
      }
#pragma unroll
    for (int nt = 0; nt < 2; ++nt)
#pragma unroll
      for (int r = 0; r < 4; ++r)
        outp[(row0 + rt + quad * 4 + r) * 256 + n0c + ct + nt * 16 + l15] = oacc[nt][r];
  }
}

// ---------------------------------------------------------------------------
extern "C" void kernel_launch(void* const* d_in, const int* in_sizes, int n_in,
                              void* d_out, int out_size, void* d_ws, size_t ws_size,
                              hipStream_t stream) {
  const float* go     = (const float*)d_in[0];
  const float* node_h = (const float*)d_in[1];
  const float* Wq     = (const float*)d_in[2];
  const float* Wk     = (const float*)d_in[3];
  const float* Wv     = (const float*)d_in[4];
  const float* Wproj  = (const float*)d_in[5];
  const int*   lens   = (const int*)d_in[6];

  const int T = in_sizes[0] / HD;   // 1024
  const int N = in_sizes[1] / HD;   // 24576
  const int B = in_sizes[6];        // 16
  const int NSPL = N >> 10;         // 24 (lens are multiples of 1024)
  const int QX = T >> 7;            // 8
  const int KB = N >> 7;            // 192

  // workspace carve; Opart/Lpart overlay nodebf (dead after QKV GEMMs)
  char* p = (char*)d_ws;
  ushort* Kgb  = (ushort*)p;  p += (size_t)N * HD * 2;       // 12.6 MB
  ushort* Vtb  = (ushort*)p;  p += (size_t)N * HD * 2;       // 12.6 MB
  ushort* Qbf  = (ushort*)p;  p += (size_t)T * HD * 2;
  ushort* gobf = (ushort*)p;  p += (size_t)T * HD * 2;
  ushort* ctxb = (ushort*)p;  p += (size_t)B * T * HD * 2;   // 8.4 MB (unused)
  ushort* wbf  = (ushort*)p;  p += (size_t)4 * HD * HD * 2;
  ushort* nodebf = (ushort*)p;                               // 12.6 MB ...
  float* Opart = (float*)p;   p += (size_t)NSPL * HEADS * QX * 8192 * 4;  // 25.2 MB
  float* Lpart = (float*)p;   p += (size_t)NSPL * HEADS * QX * 128 * 4;   // 0.4 MB
  (void)ctxb;

  cvt_fused<<<((T + N + 1024) * 32 + 255) / 256, 256, 0, stream>>>(
      go, node_h, Wq, Wk, Wv, Wproj, gobf, nodebf, wbf, T, N);

  qkv_gemm<<<(QX + 2 * KB) * 2, 256, 0, stream>>>(gobf, nodebf, wbf, Qbf, Kgb,
                                                  Vtb, T, N);

  attn_split<<<QX * HEADS * NSPL, 256, 0, stream>>>(Qbf, Kgb, Vtb, lens,
                                                    Opart, Lpart, T, N, B);

  combine_proj<<<(B * T) / 32, 256, 0, stream>>>(Opart, Lpart, lens,
                                                 wbf + (size_t)3 * HD * HD,
                                                 (float*)d_out, T);
}